// Round 1
// baseline (371.608 us; speedup 1.0000x reference)
//
#include <hip/hip_runtime.h>
#include <hip/hip_bf16.h>

#define B_SZ 8
#define N_SZ 2304   // 48*48
#define D_SZ 768
#define TEMP_INV 20.0f

typedef __attribute__((ext_vector_type(4))) float f32x4;
typedef __attribute__((ext_vector_type(8))) __bf16 bf16x8;

__device__ inline void gload16(const void* g, void* l) {
  __builtin_amdgcn_global_load_lds(
      (const __attribute__((address_space(1))) unsigned int*)g,
      (__attribute__((address_space(3))) unsigned int*)l,
      16, 0, 0);
}

// ---------------- normalize: xn = x / max(||x||,1e-12), stored bf16 ----------
__global__ __launch_bounds__(256) void normalize_k(
    const float* __restrict__ f, __hip_bfloat16* __restrict__ xn) {
  const int row = blockIdx.x;
  const int t = threadIdx.x;
  const float* r = f + (size_t)row * D_SZ;
  float v0 = r[t], v1 = r[t + 256], v2 = r[t + 512];
  float s = v0 * v0 + v1 * v1 + v2 * v2;
#pragma unroll
  for (int m = 32; m >= 1; m >>= 1) s += __shfl_xor(s, m);
  __shared__ float red[4];
  const int wid = t >> 6, lane = t & 63;
  if (lane == 0) red[wid] = s;
  __syncthreads();
  s = red[0] + red[1] + red[2] + red[3];
  const float inv = rsqrtf(fmaxf(s, 1e-24f));  // norm >= 1e-12 clamp equivalent
  __hip_bfloat16* o = xn + (size_t)row * D_SZ;
  o[t]       = __float2bfloat16(v0 * inv);
  o[t + 256] = __float2bfloat16(v1 * inv);
  o[t + 512] = __float2bfloat16(v2 * inv);
}

// ---------------- transpose: xt[b][d][n] = (bf16) x[b][n][d] -----------------
__global__ __launch_bounds__(256) void transpose_k(
    const float* __restrict__ f, __hip_bfloat16* __restrict__ xt) {
  __shared__ float tile[32][33];
  const int b = blockIdx.z;
  const int n0 = blockIdx.x * 32, d0 = blockIdx.y * 32;
  const int tx = threadIdx.x & 31, ty = threadIdx.x >> 5;  // 32 x 8
  const float* fb = f + (size_t)b * N_SZ * D_SZ;
#pragma unroll
  for (int j = 0; j < 4; ++j)
    tile[ty * 4 + j][tx] = fb[(size_t)(n0 + ty * 4 + j) * D_SZ + d0 + tx];
  __syncthreads();
  __hip_bfloat16* ob = xt + (size_t)b * D_SZ * N_SZ;
#pragma unroll
  for (int j = 0; j < 4; ++j)
    ob[(size_t)(d0 + ty * 4 + j) * N_SZ + n0 + tx] =
        __float2bfloat16(tile[tx][ty * 4 + j]);
}

// ---------------- row softmax over N_SZ logits (x20 scale folded here) -------
__global__ __launch_bounds__(256) void softmax_k(__hip_bfloat16* corr) {
  const size_t row = blockIdx.x;
  __hip_bfloat16* p = corr + row * (size_t)N_SZ;
  const int t = threadIdx.x;
  const int wid = t >> 6, lane = t & 63;
  float v[9];
  float mx = -1e30f;
#pragma unroll
  for (int j = 0; j < 9; ++j) {
    v[j] = __bfloat162float(p[t + j * 256]) * TEMP_INV;
    mx = fmaxf(mx, v[j]);
  }
#pragma unroll
  for (int m = 32; m >= 1; m >>= 1) mx = fmaxf(mx, __shfl_xor(mx, m));
  __shared__ float redm[4];
  if (lane == 0) redm[wid] = mx;
  __syncthreads();
  mx = fmaxf(fmaxf(redm[0], redm[1]), fmaxf(redm[2], redm[3]));
  float sum = 0.f;
#pragma unroll
  for (int j = 0; j < 9; ++j) {
    v[j] = __expf(v[j] - mx);
    sum += v[j];
  }
#pragma unroll
  for (int m = 32; m >= 1; m >>= 1) sum += __shfl_xor(sum, m);
  __shared__ float reds[4];
  if (lane == 0) reds[wid] = sum;
  __syncthreads();
  sum = reds[0] + reds[1] + reds[2] + reds[3];
  const float inv = 1.0f / sum;
#pragma unroll
  for (int j = 0; j < 9; ++j) p[t + j * 256] = __float2bfloat16(v[j] * inv);
}

// ---------------- 128x128 bf16 MFMA GEMM (m97 structure) ---------------------
// MODE 0: C_bf16[row][col] = sum_k A[row][k]*B[col][k]   (A=B=xn, corr out)
// MODE 1: Fout = 0.5*Fin + 0.5*(A @ Bt)  where Bt staged from xt rows (=cols)
template <int MODE>
__global__ __launch_bounds__(256) void gemm_k(
    const __hip_bfloat16* __restrict__ A, const __hip_bfloat16* __restrict__ Bm,
    __hip_bfloat16* __restrict__ Cbf, const float* __restrict__ Fin,
    float* __restrict__ Fout, const int K, const int lda, const int ldb,
    const long long batchA, const long long batchB, const int ldc,
    const long long batchC) {
  __shared__ __align__(16) short lds_a[128 * 64];
  __shared__ __align__(16) short lds_b[128 * 64];
  const int b = blockIdx.z;
  const short* Ab =
      (const short*)A + (size_t)b * batchA + (size_t)blockIdx.x * 128 * lda;
  const short* Bb =
      (const short*)Bm + (size_t)b * batchB + (size_t)blockIdx.y * 128 * ldb;
  const int tid = threadIdx.x;
  const int wid = tid >> 6, lane = tid & 63;
  const int wr = wid >> 1, wc = wid & 1;
  const int fr = lane & 15, fk = lane >> 4;

  f32x4 acc[4][4];
#pragma unroll
  for (int i = 0; i < 4; ++i)
#pragma unroll
    for (int j = 0; j < 4; ++j) acc[i][j] = (f32x4)0.f;

  for (int k0 = 0; k0 < K; k0 += 64) {
    // stage 128x64 bf16 A-tile and B-tile, 16B per lane per call
#pragma unroll
    for (int it = 0; it < 4; ++it) {
      const int cc = it * 4 + wid;          // 1KB chunk index (wave-uniform)
      const int e = cc * 512 + lane * 8;    // element index in [128][64]
      const int r = e >> 6, c = e & 63;
      gload16(Ab + (size_t)r * lda + k0 + c, &lds_a[cc * 512]);
      gload16(Bb + (size_t)r * ldb + k0 + c, &lds_b[cc * 512]);
    }
    asm volatile("s_waitcnt vmcnt(0)" ::: "memory");
    __syncthreads();
#pragma unroll
    for (int kk = 0; kk < 2; ++kk) {
      bf16x8 af[4], bq[4];
#pragma unroll
      for (int mi = 0; mi < 4; ++mi)
        af[mi] = *(const bf16x8*)&lds_a[(wr * 64 + mi * 16 + fr) * 64 +
                                        kk * 32 + fk * 8];
#pragma unroll
      for (int ni = 0; ni < 4; ++ni)
        bq[ni] = *(const bf16x8*)&lds_b[(wc * 64 + ni * 16 + fr) * 64 +
                                        kk * 32 + fk * 8];
#pragma unroll
      for (int mi = 0; mi < 4; ++mi)
#pragma unroll
        for (int ni = 0; ni < 4; ++ni)
          acc[mi][ni] = __builtin_amdgcn_mfma_f32_16x16x32_bf16(
              af[mi], bq[ni], acc[mi][ni], 0, 0, 0);
    }
    __syncthreads();
  }

  // epilogue. C/D layout (verified m89/m91): col = lane&15, row = (lane>>4)*4+r
  const int row0 = blockIdx.x * 128 + wr * 64 + fk * 4;
  const int col0 = blockIdx.y * 128 + wc * 64 + fr;
  if (MODE == 0) {
    __hip_bfloat16* Cb = Cbf + (size_t)b * batchC;
#pragma unroll
    for (int mi = 0; mi < 4; ++mi)
#pragma unroll
      for (int ni = 0; ni < 4; ++ni)
#pragma unroll
        for (int r = 0; r < 4; ++r)
          Cb[(size_t)(row0 + mi * 16 + r) * ldc + (col0 + ni * 16)] =
              __float2bfloat16(acc[mi][ni][r]);
  } else {
    const size_t base = (size_t)b * batchC;
#pragma unroll
    for (int mi = 0; mi < 4; ++mi)
#pragma unroll
      for (int ni = 0; ni < 4; ++ni)
#pragma unroll
        for (int r = 0; r < 4; ++r) {
          const size_t idx =
              base + (size_t)(row0 + mi * 16 + r) * ldc + (col0 + ni * 16);
          Fout[idx] = 0.5f * Fin[idx] + 0.5f * acc[mi][ni][r];
        }
  }
}

extern "C" void kernel_launch(void* const* d_in, const int* in_sizes, int n_in,
                              void* d_out, int out_size, void* d_ws,
                              size_t ws_size, hipStream_t stream) {
  const float* feat = (const float*)d_in[0];
  float* out = (float*)d_out;
  char* ws = (char*)d_ws;
  const size_t ND = (size_t)B_SZ * N_SZ * D_SZ;  // 14,155,776
  __hip_bfloat16* xn = (__hip_bfloat16*)ws;                  // 28.3 MB
  __hip_bfloat16* xt = (__hip_bfloat16*)(ws + ND * 2);       // 28.3 MB
  __hip_bfloat16* corr = (__hip_bfloat16*)(ws + ND * 4);     // 84.9 MB

  normalize_k<<<B_SZ * N_SZ, 256, 0, stream>>>(feat, xn);
  transpose_k<<<dim3(N_SZ / 32, D_SZ / 32, B_SZ), 256, 0, stream>>>(feat, xt);
  gemm_k<0><<<dim3(N_SZ / 128, N_SZ / 128, B_SZ), 256, 0, stream>>>(
      xn, xn, corr, nullptr, nullptr, D_SZ, D_SZ, D_SZ,
      (long long)N_SZ * D_SZ, (long long)N_SZ * D_SZ, N_SZ,
      (long long)N_SZ * N_SZ);
  softmax_k<<<B_SZ * N_SZ, 256, 0, stream>>>(corr);
  gemm_k<1><<<dim3(N_SZ / 128, D_SZ / 128, B_SZ), 256, 0, stream>>>(
      corr, xt, nullptr, feat, out, N_SZ, N_SZ, N_SZ,
      (long long)N_SZ * N_SZ, (long long)D_SZ * N_SZ, D_SZ,
      (long long)N_SZ * D_SZ);
}

// Round 3
// 305.183 us; speedup vs baseline: 1.2177x; 1.2177x over previous
//
#include <hip/hip_runtime.h>
#include <hip/hip_bf16.h>

#define B_SZ 8
#define N_SZ 2304   // 48*48
#define D_SZ 768
#define TEMP_INV 20.0f

typedef __attribute__((ext_vector_type(4))) float f32x4;
typedef __attribute__((ext_vector_type(8))) __bf16 bf16x8;

__device__ inline void gload16(const void* g, void* l) {
  __builtin_amdgcn_global_load_lds(
      (const __attribute__((address_space(1))) unsigned int*)g,
      (__attribute__((address_space(3))) unsigned int*)l,
      16, 0, 0);
}

// ---------------- normalize: xn = x / max(||x||,1e-12), stored bf16 ----------
__global__ __launch_bounds__(256) void normalize_k(
    const float* __restrict__ f, __hip_bfloat16* __restrict__ xn) {
  const int row = blockIdx.x;
  const int t = threadIdx.x;
  const float* r = f + (size_t)row * D_SZ;
  float v0 = r[t], v1 = r[t + 256], v2 = r[t + 512];
  float s = v0 * v0 + v1 * v1 + v2 * v2;
#pragma unroll
  for (int m = 32; m >= 1; m >>= 1) s += __shfl_xor(s, m);
  __shared__ float red[4];
  const int wid = t >> 6, lane = t & 63;
  if (lane == 0) red[wid] = s;
  __syncthreads();
  s = red[0] + red[1] + red[2] + red[3];
  const float inv = rsqrtf(fmaxf(s, 1e-24f));
  __hip_bfloat16* o = xn + (size_t)row * D_SZ;
  o[t]       = __float2bfloat16(v0 * inv);
  o[t + 256] = __float2bfloat16(v1 * inv);
  o[t + 512] = __float2bfloat16(v2 * inv);
}

// ---------------- transpose: xt[b][d][n] = (bf16) x[b][n][d] -----------------
__global__ __launch_bounds__(256) void transpose_k(
    const float* __restrict__ f, __hip_bfloat16* __restrict__ xt) {
  __shared__ float tile[32][33];
  const int b = blockIdx.z;
  const int n0 = blockIdx.x * 32, d0 = blockIdx.y * 32;
  const int tx = threadIdx.x & 31, ty = threadIdx.x >> 5;  // 32 x 8
  const float* fb = f + (size_t)b * N_SZ * D_SZ;
#pragma unroll
  for (int j = 0; j < 4; ++j)
    tile[ty * 4 + j][tx] = fb[(size_t)(n0 + ty * 4 + j) * D_SZ + d0 + tx];
  __syncthreads();
  __hip_bfloat16* ob = xt + (size_t)b * D_SZ * N_SZ;
#pragma unroll
  for (int j = 0; j < 4; ++j)
    ob[(size_t)(d0 + ty * 4 + j) * N_SZ + n0 + tx] =
        __float2bfloat16(tile[tx][ty * 4 + j]);
}

// ---------------- row softmax over N_SZ logits (x20 scale folded here) -------
__global__ __launch_bounds__(256) void softmax_k(__hip_bfloat16* corr) {
  const size_t row = blockIdx.x;
  __hip_bfloat16* p = corr + row * (size_t)N_SZ;
  const int t = threadIdx.x;
  const int wid = t >> 6, lane = t & 63;
  float v[9];
  float mx = -1e30f;
#pragma unroll
  for (int j = 0; j < 9; ++j) {
    v[j] = __bfloat162float(p[t + j * 256]) * TEMP_INV;
    mx = fmaxf(mx, v[j]);
  }
#pragma unroll
  for (int m = 32; m >= 1; m >>= 1) mx = fmaxf(mx, __shfl_xor(mx, m));
  __shared__ float redm[4];
  if (lane == 0) redm[wid] = mx;
  __syncthreads();
  mx = fmaxf(fmaxf(redm[0], redm[1]), fmaxf(redm[2], redm[3]));
  float sum = 0.f;
#pragma unroll
  for (int j = 0; j < 9; ++j) {
    v[j] = __expf(v[j] - mx);
    sum += v[j];
  }
#pragma unroll
  for (int m = 32; m >= 1; m >>= 1) sum += __shfl_xor(sum, m);
  __shared__ float reds[4];
  if (lane == 0) reds[wid] = sum;
  __syncthreads();
  sum = reds[0] + reds[1] + reds[2] + reds[3];
  const float inv = 1.0f / sum;
#pragma unroll
  for (int j = 0; j < 9; ++j) p[t + j * 256] = __float2bfloat16(v[j] * inv);
}

// ============ 256x256 8-phase bf16 MFMA GEMM (T1+T2+T3+T4+T5) ================
// LDS ring: 4 slots x 32KB. Slot = K-half h (32 k-cols): A[256][32] + B[256][32].
// Per phase: {4|8} ds_read_b128 frags, stage one 16KB part (2 gload_lds),
// barrier, setprio(1), 16 MFMA, setprio(0), [vmcnt(4) at tile end], barrier.
// Swizzle: LDS linear granule gL of row r holds global granule gL^(r&3);
// staged via pre-swizzled global source, read via swizzled ds_read addr.
// MODE 0: C_bf16 = A·B^T (row-K x row-K).  MODE 1: Fout = .5*Fin + .5*(A·B^T).
template <int MODE>
__global__ __launch_bounds__(512, 2) void gemm8_k(
    const __hip_bfloat16* __restrict__ A, const __hip_bfloat16* __restrict__ Bm,
    __hip_bfloat16* __restrict__ Cbf, const float* __restrict__ Fin,
    float* __restrict__ Fout, const int K, const int lda, const int ldb,
    const long long batchA, const long long batchB, const int ldc,
    const long long batchC, const int gx, const int gy, const int cpx) {
  __shared__ __align__(16) short lds[65536];  // 128 KB
  // XCD-bijective blockIdx swizzle (nwg % 8 == 0 for both launches)
  const int o = blockIdx.x + gx * (blockIdx.y + gy * blockIdx.z);
  const int l = (o & 7) * cpx + (o >> 3);
  const int bx = l % gx;
  const int byz = l / gx;
  const int by = byz % gy;
  const int b = byz / gy;

  const int tid = threadIdx.x;
  const int wid = tid >> 6, lane = tid & 63;
  const int wr = wid >> 2, wc = wid & 3;     // 2 x 4 wave grid
  const int fr = lane & 15, fk = lane >> 4;

  const short* Ab = (const short*)A + (size_t)b * batchA + (size_t)bx * 256 * lda;
  const short* Bb = (const short*)Bm + (size_t)b * batchB + (size_t)by * 256 * ldb;

  // staging map: thread -> (row r, linear granule tid&3); source granule
  // pre-swizzled so LDS dest stays linear (rule #21).
  const int r0 = tid >> 2;
  const int gsw = ((tid & 3) ^ (r0 & 3)) * 8;
  const short* sa0 = Ab + (size_t)r0 * lda + gsw;
  const short* sa1 = Ab + (size_t)(r0 + 128) * lda + gsw;
  const short* sb0 = Bb + (size_t)r0 * ldb + gsw;
  const short* sb1 = Bb + (size_t)(r0 + 128) * ldb + gsw;
  const int dstT = tid * 8;  // shorts within 8KB L-region

  // frag read offsets (shorts), swizzled granule: row&3 == fr&3 always
  const int g2 = (fk ^ (fr & 3)) * 8;
  int aOff[8], bOff[4];
#pragma unroll
  for (int mi = 0; mi < 8; ++mi) aOff[mi] = (wr * 128 + mi * 16 + fr) * 32 + g2;
#pragma unroll
  for (int ni = 0; ni < 4; ++ni) bOff[ni] = 8192 + (wc * 64 + ni * 16 + fr) * 32 + g2;

  f32x4 acc[8][4];
#pragma unroll
  for (int i = 0; i < 8; ++i)
#pragma unroll
    for (int j = 0; j < 4; ++j) acc[i][j] = (f32x4)0.f;

  const int T = K >> 6;      // K-tiles of 64
  const int UMAX = 4 * T;    // stage units: half h = u>>1 (k-cols h*32), part u&1

  auto stage = [&](int u) {
    const int kOff = (u >> 1) * 32;
    short* d = &lds[((u >> 1) & 3) * 16384 + (u & 1) * 8192 + dstT];
    if (u & 1) {
      gload16(sb0 + kOff, d);
      gload16(sb1 + kOff, d + 4096);
    } else {
      gload16(sa0 + kOff, d);
      gload16(sa1 + kOff, d + 4096);
    }
  };

  // prologue: halves 0,1,2 (units 0..5); wait until halves 0,1 landed
#pragma unroll
  for (int u = 0; u < 6; ++u) stage(u);
  asm volatile("s_waitcnt vmcnt(4)" ::: "memory");
  __builtin_amdgcn_s_barrier();

  bf16x8 bq[4], af[4];
  for (int t = 0; t < T; ++t) {
#pragma unroll
    for (int q = 0; q < 4; ++q) {
      const int kk = q >> 1;
      const int baseS = ((2 * t + kk) & 3) * 16384;
      if ((q & 1) == 0) {
#pragma unroll
        for (int ni = 0; ni < 4; ++ni)
          bq[ni] = *(const bf16x8*)&lds[baseS + bOff[ni]];
      }
#pragma unroll
      for (int i = 0; i < 4; ++i)
        af[i] = *(const bf16x8*)&lds[baseS + aOff[(q & 1) * 4 + i]];
      const int u = 4 * t + q + 6;
      if (u < UMAX) stage(u);
      __builtin_amdgcn_s_barrier();
      __builtin_amdgcn_s_setprio(1);
#pragma unroll
      for (int i = 0; i < 4; ++i)
#pragma unroll
        for (int ni = 0; ni < 4; ++ni)
          acc[(q & 1) * 4 + i][ni] = __builtin_amdgcn_mfma_f32_16x16x32_bf16(
              af[i], bq[ni], acc[(q & 1) * 4 + i][ni], 0, 0, 0);
      __builtin_amdgcn_s_setprio(0);
      if (q == 3) {
        if (t < T - 2) {
          asm volatile("s_waitcnt vmcnt(4)" ::: "memory");  // counted, never 0
        } else if (t == T - 2) {
          asm volatile("s_waitcnt vmcnt(0)" ::: "memory");  // last-tile drain
        }
      }
      __builtin_amdgcn_s_barrier();
    }
  }

  // epilogue. C/D layout: col = lane&15, row = (lane>>4)*4 + r
  const int row0 = bx * 256 + wr * 128 + fk * 4;
  const int col0 = by * 256 + wc * 64 + fr;
  if (MODE == 0) {
    __hip_bfloat16* Cb = Cbf + (size_t)b * batchC;
#pragma unroll
    for (int mi = 0; mi < 8; ++mi)
#pragma unroll
      for (int ni = 0; ni < 4; ++ni)
#pragma unroll
        for (int r = 0; r < 4; ++r)
          Cb[(size_t)(row0 + mi * 16 + r) * ldc + (col0 + ni * 16)] =
              __float2bfloat16(acc[mi][ni][r]);
  } else {
    const size_t base = (size_t)b * batchC;
#pragma unroll
    for (int mi = 0; mi < 8; ++mi)
#pragma unroll
      for (int ni = 0; ni < 4; ++ni)
#pragma unroll
        for (int r = 0; r < 4; ++r) {
          const size_t idx =
              base + (size_t)(row0 + mi * 16 + r) * ldc + (col0 + ni * 16);
          Fout[idx] = 0.5f * Fin[idx] + 0.5f * acc[mi][ni][r];
        }
  }
}

extern "C" void kernel_launch(void* const* d_in, const int* in_sizes, int n_in,
                              void* d_out, int out_size, void* d_ws,
                              size_t ws_size, hipStream_t stream) {
  const float* feat = (const float*)d_in[0];
  float* out = (float*)d_out;
  char* ws = (char*)d_ws;
  const size_t ND = (size_t)B_SZ * N_SZ * D_SZ;  // 14,155,776
  __hip_bfloat16* xn = (__hip_bfloat16*)ws;               // 28.3 MB
  __hip_bfloat16* xt = (__hip_bfloat16*)(ws + ND * 2);    // 28.3 MB
  __hip_bfloat16* corr = (__hip_bfloat16*)(ws + ND * 4);  // 84.9 MB

  normalize_k<<<B_SZ * N_SZ, 256, 0, stream>>>(feat, xn);
  transpose_k<<<dim3(N_SZ / 32, D_SZ / 32, B_SZ), 256, 0, stream>>>(feat, xt);
  // GEMM1: corr = xn . xn^T   grid 9x9x8 = 648 blocks (648/8 = 81)
  gemm8_k<0><<<dim3(9, 9, 8), 512, 0, stream>>>(
      xn, xn, corr, nullptr, nullptr, D_SZ, D_SZ, D_SZ,
      (long long)N_SZ * D_SZ, (long long)N_SZ * D_SZ, N_SZ,
      (long long)N_SZ * N_SZ, 9, 9, 81);
  softmax_k<<<B_SZ * N_SZ, 256, 0, stream>>>(corr);
  // GEMM2: out = .5*feat + .5*(W . xt^T)  grid 9x3x8 = 216 blocks (216/8 = 27)
  gemm8_k<1><<<dim3(9, 3, 8), 512, 0, stream>>>(
      corr, xt, nullptr, feat, out, N_SZ, N_SZ, N_SZ,
      (long long)N_SZ * N_SZ, (long long)D_SZ * N_SZ, D_SZ,
      (long long)N_SZ * D_SZ, 9, 3, 27);
}

// Round 4
// 304.787 us; speedup vs baseline: 1.2192x; 1.0013x over previous
//
#include <hip/hip_runtime.h>
#include <hip/hip_bf16.h>

#define B_SZ 8
#define N_SZ 2304   // 48*48
#define D_SZ 768
#define TEMP_INV 20.0f

typedef __attribute__((ext_vector_type(4))) float f32x4;
typedef __attribute__((ext_vector_type(8))) __bf16 bf16x8;
typedef __attribute__((ext_vector_type(8))) unsigned short u16x8;

__device__ inline void gload16(const void* g, void* l) {
  __builtin_amdgcn_global_load_lds(
      (const __attribute__((address_space(1))) unsigned int*)g,
      (__attribute__((address_space(3))) unsigned int*)l,
      16, 0, 0);
}

__device__ inline float b2f(unsigned short h) {
  union { float f; unsigned u; } x;
  x.u = ((unsigned)h) << 16;
  return x.f;
}
__device__ inline unsigned short f2b(float f) {
  __hip_bfloat16 t = __float2bfloat16(f);
  return *reinterpret_cast<unsigned short*>(&t);
}

// ---------------- normalize: xn = x / max(||x||,1e-12), stored bf16 ----------
__global__ __launch_bounds__(256) void normalize_k(
    const float* __restrict__ f, __hip_bfloat16* __restrict__ xn) {
  const int row = blockIdx.x;
  const int t = threadIdx.x;
  const float* r = f + (size_t)row * D_SZ;
  float v0 = r[t], v1 = r[t + 256], v2 = r[t + 512];
  float s = v0 * v0 + v1 * v1 + v2 * v2;
#pragma unroll
  for (int m = 32; m >= 1; m >>= 1) s += __shfl_xor(s, m);
  __shared__ float red[4];
  const int wid = t >> 6, lane = t & 63;
  if (lane == 0) red[wid] = s;
  __syncthreads();
  s = red[0] + red[1] + red[2] + red[3];
  const float inv = rsqrtf(fmaxf(s, 1e-24f));
  __hip_bfloat16* o = xn + (size_t)row * D_SZ;
  o[t]       = __float2bfloat16(v0 * inv);
  o[t + 256] = __float2bfloat16(v1 * inv);
  o[t + 512] = __float2bfloat16(v2 * inv);
}

// ---------------- transpose: xt[b][d][n] = (bf16) x[b][n][d] -----------------
__global__ __launch_bounds__(256) void transpose_k(
    const float* __restrict__ f, __hip_bfloat16* __restrict__ xt) {
  __shared__ float tile[32][33];
  const int b = blockIdx.z;
  const int n0 = blockIdx.x * 32, d0 = blockIdx.y * 32;
  const int tx = threadIdx.x & 31, ty = threadIdx.x >> 5;  // 32 x 8
  const float* fb = f + (size_t)b * N_SZ * D_SZ;
#pragma unroll
  for (int j = 0; j < 4; ++j)
    tile[ty * 4 + j][tx] = fb[(size_t)(n0 + ty * 4 + j) * D_SZ + d0 + tx];
  __syncthreads();
  __hip_bfloat16* ob = xt + (size_t)b * D_SZ * N_SZ;
#pragma unroll
  for (int j = 0; j < 4; ++j)
    ob[(size_t)(d0 + ty * 4 + j) * N_SZ + n0 + tx] =
        __float2bfloat16(tile[tx][ty * 4 + j]);
}

// --------- row softmax, 8 rows/block, 32 lanes/row, bf16x8 IO, no LDS --------
// row = 2304 elems = 288 x bf16x8 chunks; lane handles chunks sub+32j, j=0..8
__global__ __launch_bounds__(256) void softmax_k(__hip_bfloat16* corr) {
  const int t = threadIdx.x;
  const int sub = t & 31;
  const size_t row = (size_t)blockIdx.x * 8 + (t >> 5);
  unsigned short* p = (unsigned short*)(corr + row * N_SZ);
  u16x8 q[9];
  float v[72];
  float mx = -1e30f;
#pragma unroll
  for (int j = 0; j < 9; ++j) {
    q[j] = *(const u16x8*)&p[(sub + 32 * j) * 8];
#pragma unroll
    for (int e = 0; e < 8; ++e) {
      v[j * 8 + e] = b2f(q[j][e]) * TEMP_INV;
      mx = fmaxf(mx, v[j * 8 + e]);
    }
  }
#pragma unroll
  for (int m = 16; m >= 1; m >>= 1) mx = fmaxf(mx, __shfl_xor(mx, m, 32));
  float sum = 0.f;
#pragma unroll
  for (int i = 0; i < 72; ++i) {
    v[i] = __expf(v[i] - mx);
    sum += v[i];
  }
#pragma unroll
  for (int m = 16; m >= 1; m >>= 1) sum += __shfl_xor(sum, m, 32);
  const float inv = 1.0f / sum;
#pragma unroll
  for (int j = 0; j < 9; ++j) {
    u16x8 o;
#pragma unroll
    for (int e = 0; e < 8; ++e) o[e] = f2b(v[j * 8 + e] * inv);
    *(u16x8*)&p[(sub + 32 * j) * 8] = o;
  }
}

// ============ 256x256 8-phase bf16 MFMA GEMM (T1+T2+T3+T4+T5) ================
// LDS ring: 4 slots x 32KB. Slot = K-half h (32 k-cols): A[256][32] + B[256][32].
// Per phase: {4|8} ds_read_b128 frags, stage one 16KB part (2 gload_lds),
// barrier, setprio(1), 16 MFMA, setprio(0), [counted vmcnt at tile end], barrier.
// NOTE: waitcnt asms are clobber-less (m201 style) — a "memory" clobber makes
// the compiler insert its own vmcnt(0) drains, defeating the counted pipeline.
// MODE 0: C_bf16 = A·B^T (row-K x row-K).  MODE 1: Fout = .5*Fin + .5*(A·B^T).
template <int MODE>
__global__ __launch_bounds__(512, 2) void gemm8_k(
    const __hip_bfloat16* __restrict__ A, const __hip_bfloat16* __restrict__ Bm,
    __hip_bfloat16* __restrict__ Cbf, const float* __restrict__ Fin,
    float* __restrict__ Fout, const int K, const int lda, const int ldb,
    const long long batchA, const long long batchB, const int ldc,
    const long long batchC, const int gx, const int gy, const int cpx) {
  __shared__ __align__(16) short lds[65536];  // 128 KB
  // XCD-bijective blockIdx swizzle (nwg % 8 == 0 for both launches)
  const int o = blockIdx.x + gx * (blockIdx.y + gy * blockIdx.z);
  const int l = (o & 7) * cpx + (o >> 3);
  const int bx = l % gx;
  const int byz = l / gx;
  const int by = byz % gy;
  const int b = byz / gy;

  const int tid = threadIdx.x;
  const int wid = tid >> 6, lane = tid & 63;
  const int wr = wid >> 2, wc = wid & 3;     // 2 x 4 wave grid
  const int fr = lane & 15, fk = lane >> 4;

  const short* Ab = (const short*)A + (size_t)b * batchA + (size_t)bx * 256 * lda;
  const short* Bb = (const short*)Bm + (size_t)b * batchB + (size_t)by * 256 * ldb;

  // staging map: thread -> (row r, linear granule tid&3); source granule
  // pre-swizzled so LDS dest stays linear (rule #21).
  const int r0 = tid >> 2;
  const int gsw = ((tid & 3) ^ (r0 & 3)) * 8;
  const short* sa0 = Ab + (size_t)r0 * lda + gsw;
  const short* sa1 = Ab + (size_t)(r0 + 128) * lda + gsw;
  const short* sb0 = Bb + (size_t)r0 * ldb + gsw;
  const short* sb1 = Bb + (size_t)(r0 + 128) * ldb + gsw;
  const int dstT = tid * 8;  // shorts within 8KB L-region

  // frag read offsets (shorts), swizzled granule: row&3 == fr&3 always
  const int g2 = (fk ^ (fr & 3)) * 8;
  int aOff[8], bOff[4];
#pragma unroll
  for (int mi = 0; mi < 8; ++mi) aOff[mi] = (wr * 128 + mi * 16 + fr) * 32 + g2;
#pragma unroll
  for (int ni = 0; ni < 4; ++ni) bOff[ni] = 8192 + (wc * 64 + ni * 16 + fr) * 32 + g2;

  f32x4 acc[8][4];
#pragma unroll
  for (int i = 0; i < 8; ++i)
#pragma unroll
    for (int j = 0; j < 4; ++j) acc[i][j] = (f32x4)0.f;

  const int T = K >> 6;      // K-tiles of 64
  const int UMAX = 4 * T;    // stage units: half h = u>>1 (k-cols h*32), part u&1

  auto stage = [&](int u) {
    const int kOff = (u >> 1) * 32;
    short* d = &lds[((u >> 1) & 3) * 16384 + (u & 1) * 8192 + dstT];
    if (u & 1) {
      gload16(sb0 + kOff, d);
      gload16(sb1 + kOff, d + 4096);
    } else {
      gload16(sa0 + kOff, d);
      gload16(sa1 + kOff, d + 4096);
    }
  };

  // prologue: halves 0,1,2 (units 0..5); wait until halves 0,1 landed
#pragma unroll
  for (int u = 0; u < 6; ++u) stage(u);
  asm volatile("s_waitcnt vmcnt(4)");
  __builtin_amdgcn_s_barrier();

  bf16x8 bq[4], af[4];
  for (int t = 0; t < T; ++t) {
#pragma unroll
    for (int q = 0; q < 4; ++q) {
      const int kk = q >> 1;
      const int baseS = ((2 * t + kk) & 3) * 16384;
      if ((q & 1) == 0) {
#pragma unroll
        for (int ni = 0; ni < 4; ++ni)
          bq[ni] = *(const bf16x8*)&lds[baseS + bOff[ni]];
      }
#pragma unroll
      for (int i = 0; i < 4; ++i)
        af[i] = *(const bf16x8*)&lds[baseS + aOff[(q & 1) * 4 + i]];
      const int u = 4 * t + q + 6;
      if (u < UMAX) stage(u);
      __builtin_amdgcn_s_barrier();
      __builtin_amdgcn_s_setprio(1);
#pragma unroll
      for (int i = 0; i < 4; ++i)
#pragma unroll
        for (int ni = 0; ni < 4; ++ni)
          acc[(q & 1) * 4 + i][ni] = __builtin_amdgcn_mfma_f32_16x16x32_bf16(
              af[i], bq[ni], acc[(q & 1) * 4 + i][ni], 0, 0, 0);
      __builtin_amdgcn_s_setprio(0);
      if (q == 3) {
        if (t < T - 2) {
          asm volatile("s_waitcnt vmcnt(4)");  // counted, never 0
        } else if (t == T - 2) {
          asm volatile("s_waitcnt vmcnt(0)");  // last-tile drain
        }
      }
      __builtin_amdgcn_s_barrier();
    }
  }

  // epilogue. C/D layout: col = lane&15, row = (lane>>4)*4 + r
  const int row0 = bx * 256 + wr * 128 + fk * 4;
  const int col0 = by * 256 + wc * 64 + fr;
  if (MODE == 0) {
    __hip_bfloat16* Cb = Cbf + (size_t)b * batchC;
#pragma unroll
    for (int mi = 0; mi < 8; ++mi)
#pragma unroll
      for (int ni = 0; ni < 4; ++ni)
#pragma unroll
        for (int r = 0; r < 4; ++r)
          Cb[(size_t)(row0 + mi * 16 + r) * ldc + (col0 + ni * 16)] =
              __float2bfloat16(acc[mi][ni][r]);
  } else {
    const size_t base = (size_t)b * batchC;
#pragma unroll
    for (int mi = 0; mi < 8; ++mi)
#pragma unroll
      for (int ni = 0; ni < 4; ++ni)
#pragma unroll
        for (int r = 0; r < 4; ++r) {
          const size_t idx =
              base + (size_t)(row0 + mi * 16 + r) * ldc + (col0 + ni * 16);
          Fout[idx] = 0.5f * Fin[idx] + 0.5f * acc[mi][ni][r];
        }
  }
}

extern "C" void kernel_launch(void* const* d_in, const int* in_sizes, int n_in,
                              void* d_out, int out_size, void* d_ws,
                              size_t ws_size, hipStream_t stream) {
  const float* feat = (const float*)d_in[0];
  float* out = (float*)d_out;
  char* ws = (char*)d_ws;
  const size_t ND = (size_t)B_SZ * N_SZ * D_SZ;  // 14,155,776
  __hip_bfloat16* xn = (__hip_bfloat16*)ws;               // 28.3 MB
  __hip_bfloat16* xt = (__hip_bfloat16*)(ws + ND * 2);    // 28.3 MB
  __hip_bfloat16* corr = (__hip_bfloat16*)(ws + ND * 4);  // 84.9 MB

  normalize_k<<<B_SZ * N_SZ, 256, 0, stream>>>(feat, xn);
  transpose_k<<<dim3(N_SZ / 32, D_SZ / 32, B_SZ), 256, 0, stream>>>(feat, xt);
  // GEMM1: corr = xn . xn^T   grid 9x9x8 = 648 blocks (648/8 = 81)
  gemm8_k<0><<<dim3(9, 9, 8), 512, 0, stream>>>(
      xn, xn, corr, nullptr, nullptr, D_SZ, D_SZ, D_SZ,
      (long long)N_SZ * D_SZ, (long long)N_SZ * D_SZ, N_SZ,
      (long long)N_SZ * N_SZ, 9, 9, 81);
  softmax_k<<<B_SZ * N_SZ / 8, 256, 0, stream>>>(corr);
  // GEMM2: out = .5*feat + .5*(W . xt^T)  grid 9x3x8 = 216 blocks (216/8 = 27)
  gemm8_k<1><<<dim3(9, 3, 8), 512, 0, stream>>>(
      corr, xt, nullptr, feat, out, N_SZ, N_SZ, N_SZ,
      (long long)N_SZ * N_SZ, (long long)D_SZ * N_SZ, D_SZ,
      (long long)N_SZ * D_SZ, 9, 3, 27);
}

// Round 5
// 294.533 us; speedup vs baseline: 1.2617x; 1.0348x over previous
//
#include <hip/hip_runtime.h>
#include <hip/hip_bf16.h>

#define B_SZ 8
#define N_SZ 2304   // 48*48
#define D_SZ 768
#define TEMP_INV 20.0f

typedef __attribute__((ext_vector_type(4))) float f32x4;
typedef __attribute__((ext_vector_type(8))) __bf16 bf16x8;
typedef __attribute__((ext_vector_type(8))) unsigned short u16x8;

__device__ inline void gload16(const void* g, void* l) {
  __builtin_amdgcn_global_load_lds(
      (const __attribute__((address_space(1))) unsigned int*)g,
      (__attribute__((address_space(3))) unsigned int*)l,
      16, 0, 0);
}

// inline-asm ds_read_b128: opaque to the compiler's LDS alias analysis, so no
// conservative vmcnt auto-drains get inserted before it (R4 post-mortem).
__device__ inline f32x4 dsr128(unsigned addr) {
  f32x4 d;
  asm volatile("ds_read_b128 %0, %1" : "=v"(d) : "v"(addr));
  return d;
}

__device__ inline float b2f(unsigned short h) {
  union { float f; unsigned u; } x;
  x.u = ((unsigned)h) << 16;
  return x.f;
}
__device__ inline unsigned short f2b(float f) {
  __hip_bfloat16 t = __float2bfloat16(f);
  return *reinterpret_cast<unsigned short*>(&t);
}

// ---------------- normalize: xn = x / max(||x||,1e-12), stored bf16 ----------
__global__ __launch_bounds__(256) void normalize_k(
    const float* __restrict__ f, __hip_bfloat16* __restrict__ xn) {
  const int row = blockIdx.x;
  const int t = threadIdx.x;
  const float* r = f + (size_t)row * D_SZ;
  float v0 = r[t], v1 = r[t + 256], v2 = r[t + 512];
  float s = v0 * v0 + v1 * v1 + v2 * v2;
#pragma unroll
  for (int m = 32; m >= 1; m >>= 1) s += __shfl_xor(s, m);
  __shared__ float red[4];
  const int wid = t >> 6, lane = t & 63;
  if (lane == 0) red[wid] = s;
  __syncthreads();
  s = red[0] + red[1] + red[2] + red[3];
  const float inv = rsqrtf(fmaxf(s, 1e-24f));
  __hip_bfloat16* o = xn + (size_t)row * D_SZ;
  o[t]       = __float2bfloat16(v0 * inv);
  o[t + 256] = __float2bfloat16(v1 * inv);
  o[t + 512] = __float2bfloat16(v2 * inv);
}

// ---------------- transpose: xt[b][d][n] = (bf16) x[b][n][d] -----------------
__global__ __launch_bounds__(256) void transpose_k(
    const float* __restrict__ f, __hip_bfloat16* __restrict__ xt) {
  __shared__ float tile[32][33];
  const int b = blockIdx.z;
  const int n0 = blockIdx.x * 32, d0 = blockIdx.y * 32;
  const int tx = threadIdx.x & 31, ty = threadIdx.x >> 5;  // 32 x 8
  const float* fb = f + (size_t)b * N_SZ * D_SZ;
#pragma unroll
  for (int j = 0; j < 4; ++j)
    tile[ty * 4 + j][tx] = fb[(size_t)(n0 + ty * 4 + j) * D_SZ + d0 + tx];
  __syncthreads();
  __hip_bfloat16* ob = xt + (size_t)b * D_SZ * N_SZ;
#pragma unroll
  for (int j = 0; j < 4; ++j)
    ob[(size_t)(d0 + ty * 4 + j) * N_SZ + n0 + tx] =
        __float2bfloat16(tile[tx][ty * 4 + j]);
}

// --------- row softmax, 8 rows/block, 32 lanes/row, bf16x8 IO, no LDS --------
__global__ __launch_bounds__(256) void softmax_k(__hip_bfloat16* corr) {
  const int t = threadIdx.x;
  const int sub = t & 31;
  const size_t row = (size_t)blockIdx.x * 8 + (t >> 5);
  unsigned short* p = (unsigned short*)(corr + row * N_SZ);
  u16x8 q[9];
  float v[72];
  float mx = -1e30f;
#pragma unroll
  for (int j = 0; j < 9; ++j) {
    q[j] = *(const u16x8*)&p[(sub + 32 * j) * 8];
#pragma unroll
    for (int e = 0; e < 8; ++e) {
      v[j * 8 + e] = b2f(q[j][e]) * TEMP_INV;
      mx = fmaxf(mx, v[j * 8 + e]);
    }
  }
#pragma unroll
  for (int m = 16; m >= 1; m >>= 1) mx = fmaxf(mx, __shfl_xor(mx, m, 32));
  float sum = 0.f;
#pragma unroll
  for (int i = 0; i < 72; ++i) {
    v[i] = __expf(v[i] - mx);
    sum += v[i];
  }
#pragma unroll
  for (int m = 16; m >= 1; m >>= 1) sum += __shfl_xor(sum, m, 32);
  const float inv = 1.0f / sum;
#pragma unroll
  for (int j = 0; j < 9; ++j) {
    u16x8 o;
#pragma unroll
    for (int e = 0; e < 8; ++e) o[e] = f2b(v[j * 8 + e] * inv);
    *(u16x8*)&p[(sub + 32 * j) * 8] = o;
  }
}

// ============ 256x256 8-phase bf16 MFMA GEMM (T1+T2+T3+T4+T5) ================
// LDS ring: 4 slots x 32KB; slot = K-half (32 k-cols): A[256][32]+B[256][32].
// Swizzle s(r)=(r>>1)&3 on 16B granules: staging source pre-swizzled, frag
// reads use granule fk^s(r) -> bank-base 16*fr+4*g covers all 32 banks 2x
// per 16-lane quarter (2-way = free, m136).  Frag reads are inline-asm
// ds_read_b128 + post-barrier lgkmcnt(0) + sched_barrier(0) (rule #18).
template <int MODE>
__global__ __launch_bounds__(512, 2) void gemm8_k(
    const __hip_bfloat16* __restrict__ A, const __hip_bfloat16* __restrict__ Bm,
    __hip_bfloat16* __restrict__ Cbf, const float* __restrict__ Fin,
    float* __restrict__ Fout, const int K, const int lda, const int ldb,
    const long long batchA, const long long batchB, const int ldc,
    const long long batchC, const int gx, const int gy, const int cpx) {
  __shared__ __align__(16) short lds[65536];  // 128 KB
  const int o = blockIdx.x + gx * (blockIdx.y + gy * blockIdx.z);
  const int l = (o & 7) * cpx + (o >> 3);
  const int bx = l % gx;
  const int byz = l / gx;
  const int by = byz % gy;
  const int b = byz / gy;

  const int tid = threadIdx.x;
  const int wid = tid >> 6, lane = tid & 63;
  const int wr = wid >> 2, wc = wid & 3;     // 2 x 4 wave grid
  const int fr = lane & 15, fk = lane >> 4;

  const short* Ab = (const short*)A + (size_t)b * batchA + (size_t)bx * 256 * lda;
  const short* Bb = (const short*)Bm + (size_t)b * batchB + (size_t)by * 256 * ldb;

  // staging: thread -> (row r0, LDS granule tid&3) <- global granule ^ s(r0)
  const int r0 = tid >> 2;
  const int gsw = ((tid & 3) ^ ((r0 >> 1) & 3)) * 8;
  const short* sa0 = Ab + (size_t)r0 * lda + gsw;
  const short* sa1 = Ab + (size_t)(r0 + 128) * lda + gsw;
  const short* sb0 = Bb + (size_t)r0 * ldb + gsw;
  const short* sb1 = Bb + (size_t)(r0 + 128) * ldb + gsw;
  const int dstT = tid * 8;  // shorts within 8KB L-region

  const unsigned ldsBase = (unsigned)(unsigned long long)&lds[0];
  // frag read byte offsets within a slot; granule = fk ^ s(row)
  const int g2b = (fk ^ ((fr >> 1) & 3)) * 16;  // bytes
  unsigned aOffB[8], bOffB[4];
#pragma unroll
  for (int mi = 0; mi < 8; ++mi)
    aOffB[mi] = (unsigned)((wr * 128 + mi * 16 + fr) * 64 + g2b);
#pragma unroll
  for (int ni = 0; ni < 4; ++ni)
    bOffB[ni] = (unsigned)(16384 + (wc * 64 + ni * 16 + fr) * 64 + g2b);

  f32x4 acc[8][4];
#pragma unroll
  for (int i = 0; i < 8; ++i)
#pragma unroll
    for (int j = 0; j < 4; ++j) acc[i][j] = (f32x4)0.f;

  const int T = K >> 6;
  const int UMAX = 4 * T;  // unit u: half h=u>>1 (32 k-cols), part u&1 (A / B)

  auto stage = [&](int u) {
    const int kOff = (u >> 1) * 32;
    short* d = &lds[((u >> 1) & 3) * 16384 + (u & 1) * 8192 + dstT];
    if (u & 1) {
      gload16(sb0 + kOff, d);
      gload16(sb1 + kOff, d + 4096);
    } else {
      gload16(sa0 + kOff, d);
      gload16(sa1 + kOff, d + 4096);
    }
  };

#pragma unroll
  for (int u = 0; u < 6; ++u) stage(u);
  asm volatile("s_waitcnt vmcnt(4)");
  __builtin_amdgcn_s_barrier();

  f32x4 bq[4], af[4];
  for (int t = 0; t < T; ++t) {
#pragma unroll
    for (int q = 0; q < 4; ++q) {
      const int kk = q >> 1;
      const unsigned slotB = ldsBase + (unsigned)(((2 * t + kk) & 3) * 32768);
      if ((q & 1) == 0) {
#pragma unroll
        for (int ni = 0; ni < 4; ++ni) bq[ni] = dsr128(slotB + bOffB[ni]);
      }
#pragma unroll
      for (int i = 0; i < 4; ++i)
        af[i] = dsr128(slotB + aOffB[(q & 1) * 4 + i]);
      const int u = 4 * t + q + 6;
      if (u < UMAX) stage(u);
      __builtin_amdgcn_s_barrier();
      asm volatile("s_waitcnt lgkmcnt(0)");
      __builtin_amdgcn_sched_barrier(0);
      __builtin_amdgcn_s_setprio(1);
#pragma unroll
      for (int i = 0; i < 4; ++i)
#pragma unroll
        for (int ni = 0; ni < 4; ++ni)
          acc[(q & 1) * 4 + i][ni] = __builtin_amdgcn_mfma_f32_16x16x32_bf16(
              __builtin_bit_cast(bf16x8, af[i]), __builtin_bit_cast(bf16x8, bq[ni]),
              acc[(q & 1) * 4 + i][ni], 0, 0, 0);
      __builtin_amdgcn_s_setprio(0);
      if (q == 3) {
        if (t < T - 2) {
          asm volatile("s_waitcnt vmcnt(4)");  // counted, never 0 mid-loop
        } else if (t == T - 2) {
          asm volatile("s_waitcnt vmcnt(0)");  // final drain
        }
      }
      __builtin_amdgcn_s_barrier();
    }
  }

  // epilogue. C/D layout: col = lane&15, row = (lane>>4)*4 + r
  const int row0 = bx * 256 + wr * 128 + fk * 4;
  const int col0 = by * 256 + wc * 64 + fr;
  if (MODE == 0) {
    __hip_bfloat16* Cb = Cbf + (size_t)b * batchC;
#pragma unroll
    for (int mi = 0; mi < 8; ++mi)
#pragma unroll
      for (int ni = 0; ni < 4; ++ni)
#pragma unroll
        for (int r = 0; r < 4; ++r)
          Cb[(size_t)(row0 + mi * 16 + r) * ldc + (col0 + ni * 16)] =
              __float2bfloat16(acc[mi][ni][r]);
  } else {
    const size_t base = (size_t)b * batchC;
#pragma unroll
    for (int mi = 0; mi < 8; ++mi)
#pragma unroll
      for (int ni = 0; ni < 4; ++ni)
#pragma unroll
        for (int r = 0; r < 4; ++r) {
          const size_t idx =
              base + (size_t)(row0 + mi * 16 + r) * ldc + (col0 + ni * 16);
          Fout[idx] = 0.5f * Fin[idx] + 0.5f * acc[mi][ni][r];
        }
  }
}

extern "C" void kernel_launch(void* const* d_in, const int* in_sizes, int n_in,
                              void* d_out, int out_size, void* d_ws,
                              size_t ws_size, hipStream_t stream) {
  const float* feat = (const float*)d_in[0];
  float* out = (float*)d_out;
  char* ws = (char*)d_ws;
  const size_t ND = (size_t)B_SZ * N_SZ * D_SZ;  // 14,155,776
  __hip_bfloat16* xn = (__hip_bfloat16*)ws;               // 28.3 MB
  __hip_bfloat16* xt = (__hip_bfloat16*)(ws + ND * 2);    // 28.3 MB
  __hip_bfloat16* corr = (__hip_bfloat16*)(ws + ND * 4);  // 84.9 MB

  normalize_k<<<B_SZ * N_SZ, 256, 0, stream>>>(feat, xn);
  transpose_k<<<dim3(N_SZ / 32, D_SZ / 32, B_SZ), 256, 0, stream>>>(feat, xt);
  // GEMM1: corr = xn . xn^T   grid 9x9x8 = 648 blocks
  gemm8_k<0><<<dim3(9, 9, 8), 512, 0, stream>>>(
      xn, xn, corr, nullptr, nullptr, D_SZ, D_SZ, D_SZ,
      (long long)N_SZ * D_SZ, (long long)N_SZ * D_SZ, N_SZ,
      (long long)N_SZ * N_SZ, 9, 9, 81);
  softmax_k<<<B_SZ * N_SZ / 8, 256, 0, stream>>>(corr);
  // GEMM2: out = .5*feat + .5*(W . xt^T)  grid 9x3x8 = 216 blocks
  gemm8_k<1><<<dim3(9, 3, 8), 512, 0, stream>>>(
      corr, xt, nullptr, feat, out, N_SZ, N_SZ, N_SZ,
      (long long)N_SZ * N_SZ, (long long)D_SZ * N_SZ, D_SZ,
      (long long)N_SZ * D_SZ, 9, 3, 27);
}